// Round 3
// baseline (349.848 us; speedup 1.0000x reference)
//
#include <hip/hip_runtime.h>

// HemorrhageNet: per-row Poisson-binomial count distribution over 96 probs,
// truncated/saturated at 5, binned to severity[5] = {c0, c1+c2, c3+c4, c5, 0}.
//
// R3: 4 lanes per row (24 probs/lane), 6 independent float4 loads per lane
// issued before any consumption -> 6 KiB of HBM requests in flight per wave
// (R2 had 1 load in flight: VGPR_Count=16 showed the compiler serialized the
// loads; MLP was the limiter, not BW). Only 2 butterfly levels per 16 rows
// (R2 paid 3 levels per 8 rows -> ~40% of VALU).
//
// a5 never tracked: mass conservation gives s3 = 1 - (s0+s1+s2) exactly
// (each partial distribution sums to 1; validated in R2, absmax ~1e-29).

#define THREADS 256
#define LANES_PER_ROW 4
#define ROWS_PER_BLOCK (THREADS / LANES_PER_ROW)   // 64

__global__ __launch_bounds__(THREADS, 4) void hemorrhage_kernel(
    const float* __restrict__ x1,
    const float* __restrict__ x2,
    const float* __restrict__ x3,
    float* __restrict__ out)
{
    const int t = threadIdx.x;
    const int q4 = t & 3;                               // quarter-row slot
    const int row = blockIdx.x * ROWS_PER_BLOCK + (t >> 2);
    const size_t fbase = (size_t)row * 32 + (size_t)q4 * 8;  // float index

    // ---- 6 independent 16B loads, all issued before any use ----
    const float4* s1 = (const float4*)(x1 + fbase);
    const float4* s2 = (const float4*)(x2 + fbase);
    const float4* s3 = (const float4*)(x3 + fbase);
    const float4 v0 = s1[0];
    const float4 v1 = s1[1];
    const float4 v2 = s2[0];
    const float4 v3 = s2[1];
    const float4 v4 = s3[0];
    const float4 v5 = s3[1];

    // ---- local truncated distribution over this lane's 24 probs ----
    // track a0..a4 only; a5 reconstructed by mass conservation at the end.
    float a0 = 1.0f, a1 = 0.0f, a2 = 0.0f, a3 = 0.0f, a4 = 0.0f;

#define STEP(P)                          \
    do {                                 \
        const float p_ = (P);            \
        const float q_ = 1.0f - p_;      \
        a4 = fmaf(a4, q_, a3 * p_);      \
        a3 = fmaf(a3, q_, a2 * p_);      \
        a2 = fmaf(a2, q_, a1 * p_);     \
        a1 = fmaf(a1, q_, a0 * p_);      \
        a0 = a0 * q_;                    \
    } while (0)
    // (initial zeros constant-fold: the first 4 steps cost 3/5/7/9 instrs)

    STEP(v0.x); STEP(v0.y); STEP(v0.z); STEP(v0.w);
    STEP(v1.x); STEP(v1.y); STEP(v1.z); STEP(v1.w);
    STEP(v2.x); STEP(v2.y); STEP(v2.z); STEP(v2.w);
    STEP(v3.x); STEP(v3.y); STEP(v3.z); STEP(v3.w);
    STEP(v4.x); STEP(v4.y); STEP(v4.z); STEP(v4.w);
    STEP(v5.x); STEP(v5.y); STEP(v5.z); STEP(v5.w);
#undef STEP

    // ---- 2-level butterfly combine across the 4-lane group ----
#pragma unroll
    for (int d = 1; d < LANES_PER_ROW; d <<= 1) {
        const float b0 = __shfl_xor(a0, d);
        const float b1 = __shfl_xor(a1, d);
        const float b2 = __shfl_xor(a2, d);
        const float b3 = __shfl_xor(a3, d);
        const float b4 = __shfl_xor(a4, d);

        float n0 = a0 * b0;
        float n1 = a0 * b1;
        n1 = fmaf(a1, b0, n1);
        float n2 = a0 * b2;
        n2 = fmaf(a1, b1, n2);
        n2 = fmaf(a2, b0, n2);
        float n3 = a0 * b3;
        n3 = fmaf(a1, b2, n3);
        n3 = fmaf(a2, b1, n3);
        n3 = fmaf(a3, b0, n3);
        float n4 = a0 * b4;
        n4 = fmaf(a1, b3, n4);
        n4 = fmaf(a2, b2, n4);
        n4 = fmaf(a3, b1, n4);
        n4 = fmaf(a4, b0, n4);

        a0 = n0; a1 = n1; a2 = n2; a3 = n3; a4 = n4;
    }

    // ---- severity; c5 via mass conservation ----
    const float sev0 = a0;
    const float sev1 = a1 + a2;
    const float sev2 = a3 + a4;
    const float sev3 = 1.0f - (sev0 + sev1 + sev2);   // = c5

    // ---- store: lane q4 writes element q4; lane 0 also writes the zero col ----
    float vstore = sev3;
    if (q4 == 0) vstore = sev0;
    else if (q4 == 1) vstore = sev1;
    else if (q4 == 2) vstore = sev2;

    float* orow = out + (size_t)row * 5;
    orow[q4] = vstore;
    if (q4 == 0) orow[4] = 0.0f;   // out is re-poisoned 0xAA: must write zeros
}

extern "C" void kernel_launch(void* const* d_in, const int* in_sizes, int n_in,
                              void* d_out, int out_size, void* d_ws, size_t ws_size,
                              hipStream_t stream) {
    const float* x1 = (const float*)d_in[0];
    const float* x2 = (const float*)d_in[1];
    const float* x3 = (const float*)d_in[2];
    float* out = (float*)d_out;

    const int rows = in_sizes[0] / 32;                 // 1048576
    const int blocks = rows / ROWS_PER_BLOCK;          // 16384 (exact)
    hemorrhage_kernel<<<blocks, THREADS, 0, stream>>>(x1, x2, x3, out);
}